// Round 5
// baseline (59.936 us; speedup 1.0000x reference)
//
#include <hip/hip_runtime.h>
#include <hip/hip_bf16.h>

#define BDIM 256
#define NDIM 512
#define CDIM 1000
#define RDIM 64
#define BK 64
#define NT (NDIM / BK)   // 8 K-tiles

typedef __attribute__((ext_vector_type(4))) float f32x4;
typedef __attribute__((ext_vector_type(8))) short bf16x8;

__device__ __forceinline__ uint32_t pk2(float lo, float hi) {
    unsigned short l = __builtin_bit_cast(unsigned short, __float2bfloat16(lo));
    unsigned short h = __builtin_bit_cast(unsigned short, __float2bfloat16(hi));
    return ((uint32_t)h << 16) | (uint32_t)l;
}

__device__ __forceinline__ void gload16(const void* g, void* l) {
    __builtin_amdgcn_global_load_lds(
        (const __attribute__((address_space(1))) void*)g,
        (__attribute__((address_space(3))) void*)l, 16, 0, 0);
}

// ---------------------------------------------------------------------------
// Pre-pass (proven r2/r3): x fp32 [256][512] -> bf16 swizzled tile images.
// ---------------------------------------------------------------------------
__global__ __launch_bounds__(256)
void Mahalanobis_xconv_kernel(const float* __restrict__ x, uint4* __restrict__ xws)
{
    const int tid = blockIdx.x * 256 + threadIdx.x;   // 0..16383
    const int t   = tid >> 11;                        // tile 0..7
    const int rem = tid & 2047;
    const int row = rem >> 3;                         // 0..255
    const int sIn = (rem & 7) << 4;                   // swizzled inner byte
    const int uIn = sIn ^ ((row & 7) << 4);           // unswizzled inner byte
    const int col0 = t * BK + (uIn >> 1);
    const float4* src = reinterpret_cast<const float4*>(x + (size_t)row * NDIM + col0);
    const float4 a = src[0], b = src[1];
    uint4 pk = {pk2(a.x, a.y), pk2(a.z, a.w), pk2(b.x, b.y), pk2(b.z, b.w)};
    xws[tid] = pk;
}

// ---------------------------------------------------------------------------
// Main kernel: pipelined. Per iter: {A: af frags} {B: lgkm+bar} {C: x gloads,
// W(t+2) reg prefetch} {D: MFMA} {E: convert W(t+1)->LDS + fused Sb}
// {G: vmcnt(4) counted + bar}  -- W prefetch stays in flight across barriers.
// ---------------------------------------------------------------------------
__global__ __launch_bounds__(256, 3)
void Mahalanobis_72834055405642_kernel(const char* __restrict__ xws,
                                       const float* __restrict__ w,
                                       const float* __restrict__ bias,
                                       float* __restrict__ out)
{
    __shared__ alignas(16) char lds_x[BDIM * BK * 2];        // 32 KB (single buf)
    __shared__ alignas(16) char lds_w[2 * RDIM * BK * 2];    // 16 KB (double buf)
    __shared__ alignas(16) float bias_lds[NDIM];             // 2 KB
    __shared__ float sb_lds[RDIM];                           // 256 B

    const int tid  = threadIdx.x;
    const int lane = tid & 63;
    const int wv   = tid >> 6;
    const int l15  = lane & 15;
    const int lhi  = lane >> 4;
    const int c0   = blockIdx.x;

    const int jrow = tid >> 2;      // W row 0..63
    const int jq   = tid & 3;       // k-quarter (16 floats)
    const float* wbase = w + (size_t)c0 * (RDIM * NDIM) + (size_t)jrow * NDIM + jq * 16;

    const int swr = (l15 & 7) << 4;
    const int sww = (jrow & 7) << 4;

    f32x4 acc[4][4];
    #pragma unroll
    for (int m = 0; m < 4; ++m)
        #pragma unroll
        for (int n = 0; n < 4; ++n)
            acc[m][n] = (f32x4){0.f, 0.f, 0.f, 0.f};

    float sbp = 0.f;
    f32x4 wrA[4], wrB[4];

    // convert one W tile (held in regs) -> swizzled bf16 LDS + fused fp32 Sb
    auto convW = [&](const f32x4* wr, int tt, char* dst) {
        const f32x4* bl4 = reinterpret_cast<const f32x4*>(bias_lds + tt * BK + jq * 16);
        const f32x4 b0 = bl4[0], b1 = bl4[1], b2 = bl4[2], b3 = bl4[3];
        sbp += wr[0][0]*b0[0] + wr[0][1]*b0[1] + wr[0][2]*b0[2] + wr[0][3]*b0[3]
             + wr[1][0]*b1[0] + wr[1][1]*b1[1] + wr[1][2]*b1[2] + wr[1][3]*b1[3]
             + wr[2][0]*b2[0] + wr[2][1]*b2[1] + wr[2][2]*b2[2] + wr[2][3]*b2[3]
             + wr[3][0]*b3[0] + wr[3][1]*b3[1] + wr[3][2]*b3[2] + wr[3][3]*b3[3];
        char* rowp = dst + jrow * 128;
        uint4 pa = {pk2(wr[0][0], wr[0][1]), pk2(wr[0][2], wr[0][3]),
                    pk2(wr[1][0], wr[1][1]), pk2(wr[1][2], wr[1][3])};
        uint4 pb = {pk2(wr[2][0], wr[2][1]), pk2(wr[2][2], wr[2][3]),
                    pk2(wr[3][0], wr[3][1]), pk2(wr[3][2], wr[3][3])};
        *reinterpret_cast<uint4*>(rowp + ((jq * 32) ^ sww))      = pa;
        *reinterpret_cast<uint4*>(rowp + ((jq * 32 + 16) ^ sww)) = pb;
    };

    // ================= prologue =================
    // bias -> LDS (float2/thread)
    {
        const float2 bv = *reinterpret_cast<const float2*>(bias + (size_t)c0 * NDIM + tid * 2);
        *reinterpret_cast<float2*>(bias_lds + tid * 2) = bv;
    }
    // x(0) gloads first (oldest in vmcnt ledger)
    #pragma unroll
    for (int q = 0; q < 8; ++q)
        gload16(xws + wv * 8192 + q * 1024 + lane * 16,
                lds_x + wv * 8192 + q * 1024);
    __builtin_amdgcn_sched_barrier(0);   // pin: gloads before W loads
    // W(0) -> wrB (consumed below), W(1) -> wrA
    {
        const f32x4* s0 = reinterpret_cast<const f32x4*>(wbase);
        #pragma unroll
        for (int i = 0; i < 4; ++i) wrB[i] = __builtin_nontemporal_load(s0 + i);
        const f32x4* s1 = reinterpret_cast<const f32x4*>(wbase + BK);
        #pragma unroll
        for (int i = 0; i < 4; ++i) wrA[i] = __builtin_nontemporal_load(s1 + i);
    }
    asm volatile("s_waitcnt lgkmcnt(0)" ::: "memory");   // bias ds_writes done
    __builtin_amdgcn_s_barrier();                        // bias visible to all
    __builtin_amdgcn_sched_barrier(0);
    convW(wrB, 0, lds_w);   // compiler inserts counted vmcnt for wrB (drains x(0) too)
    asm volatile("s_waitcnt vmcnt(4) lgkmcnt(0)" ::: "memory");  // x(0)+W(0) done, W(1) in flight
    __builtin_amdgcn_s_barrier();
    __builtin_amdgcn_sched_barrier(0);

    // ================= main loop =================
    #pragma unroll
    for (int t = 0; t < NT; ++t) {
        char* ldsw_cur = lds_w + (t & 1) * 8192;
        char* ldsw_nxt = lds_w + ((t & 1) ^ 1) * 8192;

        // ---- A: x frags for both k-steps (x LDS is single-buffered)
        bf16x8 af[4][2];
        #pragma unroll
        for (int m = 0; m < 4; ++m) {
            const int row = wv * 64 + m * 16 + l15;
            #pragma unroll
            for (int ks = 0; ks < 2; ++ks)
                af[m][ks] = *reinterpret_cast<const bf16x8*>(
                    lds_x + row * 128 + ((ks * 64 + lhi * 16) ^ swr));
        }

        // ---- B: frags drained; x buffer free for overwrite
        asm volatile("s_waitcnt lgkmcnt(0)" ::: "memory");
        __builtin_amdgcn_sched_barrier(0);
        __builtin_amdgcn_s_barrier();
        __builtin_amdgcn_sched_barrier(0);

        // ---- C: issue x(t+1) gloads, then W(t+2) reg prefetch (order pinned)
        if (t < NT - 1) {
            #pragma unroll
            for (int q = 0; q < 8; ++q)
                gload16(xws + (size_t)(t + 1) * 32768 + wv * 8192 + q * 1024 + lane * 16,
                        lds_x + wv * 8192 + q * 1024);
        }
        __builtin_amdgcn_sched_barrier(0);
        if (t < NT - 2) {
            const f32x4* s = reinterpret_cast<const f32x4*>(wbase + (t + 2) * BK);
            if ((t & 1) == 0) {
                #pragma unroll
                for (int i = 0; i < 4; ++i) wrB[i] = __builtin_nontemporal_load(s + i);
            } else {
                #pragma unroll
                for (int i = 0; i < 4; ++i) wrA[i] = __builtin_nontemporal_load(s + i);
            }
        }

        // ---- D: MFMA (B-frags per k-step from current W buffer)
        #pragma unroll
        for (int ks = 0; ks < 2; ++ks) {
            bf16x8 bfr[4];
            #pragma unroll
            for (int n = 0; n < 4; ++n) {
                const int row = n * 16 + l15;
                bfr[n] = *reinterpret_cast<const bf16x8*>(
                    ldsw_cur + row * 128 + ((ks * 64 + lhi * 16) ^ swr));
            }
            __builtin_amdgcn_s_setprio(1);
            #pragma unroll
            for (int m = 0; m < 4; ++m)
                #pragma unroll
                for (int n = 0; n < 4; ++n)
                    acc[m][n] = __builtin_amdgcn_mfma_f32_16x16x32_bf16(
                        af[m][ks], bfr[n], acc[m][n], 0, 0, 0);
            __builtin_amdgcn_s_setprio(0);
        }

        // ---- E: convert W(t+1) (compiler emits counted vmcnt for its regs)
        if (t < NT - 1) {
            if ((t & 1) == 0) convW(wrA, t + 1, ldsw_nxt);
            else              convW(wrB, t + 1, ldsw_nxt);
        }

        // ---- G: counted drain — x(t+1) done, W(t+2) stays in flight
        if (t < NT - 2) {
            asm volatile("s_waitcnt vmcnt(4) lgkmcnt(0)" ::: "memory");
            __builtin_amdgcn_s_barrier();
            __builtin_amdgcn_sched_barrier(0);
        } else if (t == NT - 2) {
            asm volatile("s_waitcnt vmcnt(0) lgkmcnt(0)" ::: "memory");
            __builtin_amdgcn_s_barrier();
            __builtin_amdgcn_sched_barrier(0);
        }
    }

    // ---- Sb: reduce 4 k-quarters, publish
    sbp += __shfl_xor(sbp, 1);
    sbp += __shfl_xor(sbp, 2);
    if (jq == 0) sb_lds[jrow] = sbp;
    __syncthreads();

    float sb[4];
    #pragma unroll
    for (int n = 0; n < 4; ++n) sb[n] = sb_lds[n * 16 + l15];

    // ---- epilogue: out[b,c0] = sum_r (S - Sb)^2
    #pragma unroll
    for (int m = 0; m < 4; ++m) {
        #pragma unroll
        for (int rg = 0; rg < 4; ++rg) {
            float p = 0.f;
            #pragma unroll
            for (int n = 0; n < 4; ++n) {
                const float d = acc[m][n][rg] - sb[n];
                p += d * d;
            }
            #pragma unroll
            for (int s = 1; s < 16; s <<= 1)
                p += __shfl_xor(p, s);
            if (l15 == 0) {
                const int b = wv * 64 + m * 16 + lhi * 4 + rg;
                out[(size_t)b * CDIM + c0] = p;
            }
        }
    }
}

// ---------------------------------------------------------------------------
// Fallback (round-3 proven kernel) for ws_size < 256 KB
// ---------------------------------------------------------------------------
__global__ __launch_bounds__(256, 4)
void Mahalanobis_fallback_kernel(const float* __restrict__ x,
                                 const float* __restrict__ w,
                                 const float* __restrict__ bias,
                                 float* __restrict__ out)
{
    __shared__ alignas(16) char lds_x[BDIM * BK * 2];
    __shared__ alignas(16) char lds_w[RDIM * BK * 2];
    __shared__ float sb_lds[RDIM];

    const int tid  = threadIdx.x;
    const int lane = tid & 63;
    const int wv   = tid >> 6;
    const int l15  = lane & 15;
    const int lhi  = lane >> 4;
    const int c0   = blockIdx.x;

    const int jrow = tid >> 2;
    const int jq   = tid & 3;
    const float* wbase = w + (size_t)c0 * (RDIM * NDIM) + (size_t)jrow * NDIM + jq * 16;
    const float* bbase = bias + (size_t)c0 * NDIM + jq * 16;

    f32x4 acc[4][4];
    #pragma unroll
    for (int m = 0; m < 4; ++m)
        #pragma unroll
        for (int n = 0; n < 4; ++n)
            acc[m][n] = (f32x4){0.f, 0.f, 0.f, 0.f};

    float sbp = 0.f;
    const int swr = (l15 & 7) << 4;
    const int sww = (jrow & 7) << 4;
    const int xrow = tid >> 2;
    const int xq   = tid & 3;

    for (int t = 0; t < NT; ++t) {
        const float4* wsrc = reinterpret_cast<const float4*>(wbase + t * BK);
        const float4* bsrc = reinterpret_cast<const float4*>(bbase + t * BK);
        float4 w0 = wsrc[0], w1 = wsrc[1], w2 = wsrc[2], w3 = wsrc[3];
        float4 b0 = bsrc[0], b1 = bsrc[1], b2 = bsrc[2], b3 = bsrc[3];

        #pragma unroll
        for (int p = 0; p < 4; ++p) {
            const int r = p * 64 + xrow;
            const float4* s = reinterpret_cast<const float4*>(
                x + (size_t)r * NDIM + t * BK + xq * 16);
            float4 va = s[0], vb = s[1], vc = s[2], vd = s[3];
            uint4 pa = {pk2(va.x, va.y), pk2(va.z, va.w), pk2(vb.x, vb.y), pk2(vb.z, vb.w)};
            uint4 pb = {pk2(vc.x, vc.y), pk2(vc.z, vc.w), pk2(vd.x, vd.y), pk2(vd.z, vd.w)};
            const int sw = (r & 7) << 4;
            char* rowp = lds_x + r * 128;
            *reinterpret_cast<uint4*>(rowp + ((xq * 32) ^ sw))      = pa;
            *reinterpret_cast<uint4*>(rowp + ((xq * 32 + 16) ^ sw)) = pb;
        }

        sbp += w0.x*b0.x + w0.y*b0.y + w0.z*b0.z + w0.w*b0.w
             + w1.x*b1.x + w1.y*b1.y + w1.z*b1.z + w1.w*b1.w
             + w2.x*b2.x + w2.y*b2.y + w2.z*b2.z + w2.w*b2.w
             + w3.x*b3.x + w3.y*b3.y + w3.z*b3.z + w3.w*b3.w;
        {
            char* rowp = lds_w + jrow * 128;
            uint4 pa = {pk2(w0.x, w0.y), pk2(w0.z, w0.w), pk2(w1.x, w1.y), pk2(w1.z, w1.w)};
            uint4 pb = {pk2(w2.x, w2.y), pk2(w2.z, w2.w), pk2(w3.x, w3.y), pk2(w3.z, w3.w)};
            *reinterpret_cast<uint4*>(rowp + ((jq * 32) ^ sww))      = pa;
            *reinterpret_cast<uint4*>(rowp + ((jq * 32 + 16) ^ sww)) = pb;
        }

        __syncthreads();

        #pragma unroll
        for (int ks = 0; ks < 2; ++ks) {
            bf16x8 af[4];
            bf16x8 bfr[4];
            #pragma unroll
            for (int m = 0; m < 4; ++m) {
                const int row = wv * 64 + m * 16 + l15;
                af[m] = *reinterpret_cast<const bf16x8*>(
                    lds_x + row * 128 + ((ks * 64 + lhi * 16) ^ swr));
            }
            #pragma unroll
            for (int n = 0; n < 4; ++n) {
                const int row = n * 16 + l15;
                bfr[n] = *reinterpret_cast<const bf16x8*>(
                    lds_w + row * 128 + ((ks * 64 + lhi * 16) ^ swr));
            }
            #pragma unroll
            for (int m = 0; m < 4; ++m)
                #pragma unroll
                for (int n = 0; n < 4; ++n)
                    acc[m][n] = __builtin_amdgcn_mfma_f32_16x16x32_bf16(
                        af[m], bfr[n], acc[m][n], 0, 0, 0);
        }

        __syncthreads();
    }

    sbp += __shfl_xor(sbp, 1);
    sbp += __shfl_xor(sbp, 2);
    if (jq == 0) sb_lds[jrow] = sbp;
    __syncthreads();

    float sb[4];
    #pragma unroll
    for (int n = 0; n < 4; ++n) sb[n] = sb_lds[n * 16 + l15];

    #pragma unroll
    for (int m = 0; m < 4; ++m) {
        #pragma unroll
        for (int rg = 0; rg < 4; ++rg) {
            float p = 0.f;
            #pragma unroll
            for (int n = 0; n < 4; ++n) {
                const float d = acc[m][n][rg] - sb[n];
                p += d * d;
            }
            #pragma unroll
            for (int s = 1; s < 16; s <<= 1)
                p += __shfl_xor(p, s);
            if (l15 == 0) {
                const int b = wv * 64 + m * 16 + lhi * 4 + rg;
                out[(size_t)b * CDIM + c0] = p;
            }
        }
    }
}

extern "C" void kernel_launch(void* const* d_in, const int* in_sizes, int n_in,
                              void* d_out, int out_size, void* d_ws, size_t ws_size,
                              hipStream_t stream) {
    const float* x    = (const float*)d_in[0];
    const float* w    = (const float*)d_in[1];
    const float* bias = (const float*)d_in[2];
    float* out = (float*)d_out;

    if (ws_size >= (size_t)(BDIM * NDIM * 2)) {
        hipLaunchKernelGGL(Mahalanobis_xconv_kernel, dim3(64), dim3(256), 0, stream,
                           x, (uint4*)d_ws);
        hipLaunchKernelGGL(Mahalanobis_72834055405642_kernel, dim3(CDIM), dim3(256),
                           0, stream, (const char*)d_ws, w, bias, out);
    } else {
        hipLaunchKernelGGL(Mahalanobis_fallback_kernel, dim3(CDIM), dim3(256),
                           0, stream, x, w, bias, out);
    }
}